// Round 3
// baseline (306.593 us; speedup 1.0000x reference)
//
#include <hip/hip_runtime.h>

// Problem constants
#define INC    256
#define HIN    56
#define WIN    56
#define HOUT   19
#define WOUT   58
#define KTOT   768          // K = kh*256 + c  (3 * 256)
#define XSTR   776          // LDS k-stride per w-row (bf16 units), 768 + 8 pad

typedef short frag8 __attribute__((ext_vector_type(8)));   // 8 bf16 bits (4 VGPRs)
typedef float f32x4 __attribute__((ext_vector_type(4)));   // MFMA accumulator

static __device__ __forceinline__ unsigned short f2bf(float f) {
    unsigned u = __float_as_uint(f);
    u += 0x7fffu + ((u >> 16) & 1u);      // round-to-nearest-even
    return (unsigned short)(u >> 16);
}

// ---------------------------------------------------------------------------
// prep_weff: fold the sparse einsum into dense conv weights.
//   Weff[o][k = kh*256 + c] = coeff[i(c),o] * lego[idx[i(c),o]][c&63][kh]  (bf16)
// Block (kx, o): 4 waves each do the 64-lane argmax of comb[i=wave][o][:]
// (butterfly max, first-index tie-break = jnp.argmax), then 256 threads emit
// one Weff element each. Argmax redundantly recomputed per kx (3x) - trivial.
// ---------------------------------------------------------------------------
__global__ __launch_bounds__(256) void prep_weff(
    const float* __restrict__ lego,    // [64][64][3]
    const float* __restrict__ coefs,   // [4][256][64]
    const float* __restrict__ comb,    // [4][256][64]
    unsigned short* __restrict__ Weff) // [256][768] bf16 bits
{
    __shared__ int   idxS[4];
    __shared__ float cofS[4];
    const int t  = threadIdx.x;
    const int kx = blockIdx.x;         // 0..2 (k range kx*256..)
    const int o  = blockIdx.y;         // 0..255
    const int wv = t >> 6, l = t & 63;

    float v  = comb[(wv * 256 + o) * 64 + l];
    int   bi = l;
    #pragma unroll
    for (int off = 32; off >= 1; off >>= 1) {
        float ov = __shfl_xor(v, off, 64);
        int   oi = __shfl_xor(bi, off, 64);
        if (ov > v || (ov == v && oi < bi)) { v = ov; bi = oi; }
    }
    if (l == 0) {
        idxS[wv] = bi;
        cofS[wv] = coefs[(wv * 256 + o) * 64 + bi];
    }
    __syncthreads();

    const int k  = kx * 256 + t;       // 0..767
    const int kh = k >> 8, c = k & 255;
    const int i  = c >> 6, cl = c & 63;
    float w = cofS[i] * lego[idxS[i] * 192 + cl * 3 + kh];
    Weff[(size_t)o * KTOT + k] = f2bf(w);
}

// ---------------------------------------------------------------------------
// conv_mfma: dense conv as bf16 MFMA GEMM. Block = (w-half, h, b): 1216 blocks,
// 256 threads (4 waves). Out tile: 256 o x 32 w. K = 768.
//
// Stage once: Xs[w 0..31][k 0..767] bf16 (transposed, k-contiguous rows so
// B-frags are single ds_read_b128; row stride 776 -> frag reads ~2-way free).
// One __syncthreads total. A-frags (Weff) streamed from global (L2-hot,
// 384 KB). Wave wv owns o in [wv*64, wv*64+64): 4x2 mfma_16x16x32 tiles,
// 24 K-steps -> 192 MFMA/wave. D layout (m89): col=lane&15 (w), row=quad*4+r.
// LDS 49.7 KB -> 3 blocks/CU.
// ---------------------------------------------------------------------------
__global__ __launch_bounds__(256) void conv_mfma(
    const float* __restrict__ x,             // [32][256][56][56]
    const unsigned short* __restrict__ Weff, // [256][768] bf16
    float* __restrict__ out)                 // [32][256][19][58]
{
    __shared__ unsigned short Xs[32 * XSTR]; // 49,664 B

    const int t  = threadIdx.x;
    const int wh = blockIdx.x;               // 0/1 w-half
    const int h  = blockIdx.y;               // 0..18
    const int b  = blockIdx.z;               // 0..31

    // ---- stage X transposed: Xs[w][k] = x[b][c][3h+kh-1][wh*32+w-1] ----
    const float* xb = x + (size_t)b * (INC * HIN * WIN);
    const int colbase = wh * 32 - 1;
    const int rowbase = 3 * h - 1;
    #pragma unroll 8
    for (int it = 0; it < 96; ++it) {
        int slot = it * 256 + t;
        int w = slot & 31, r = slot >> 5;    // r = k = kh*256 + c
        int kh = r >> 8, c = r & 255;
        int row = rowbase + kh;
        int col = colbase + w;
        float v = 0.f;
        if ((unsigned)row < (unsigned)HIN && (unsigned)col < (unsigned)WIN)
            v = xb[(size_t)c * (HIN * WIN) + row * WIN + col];
        Xs[w * XSTR + r] = f2bf(v);
    }
    __syncthreads();

    // ---- MFMA main loop ----
    const int l  = t & 63;
    const int lo = l & 15;                   // A row (o), B col (w)
    const int hi = l >> 4;                   // k-subgroup
    const int obase = (t >> 6) * 64;         // wave's o range

    f32x4 acc[4][2];
    #pragma unroll
    for (int ot = 0; ot < 4; ++ot)
        #pragma unroll
        for (int nt = 0; nt < 2; ++nt)
            acc[ot][nt] = (f32x4){0.f, 0.f, 0.f, 0.f};

    const unsigned short* Wp = Weff + (size_t)(obase + lo) * KTOT;

    #pragma unroll 4
    for (int ks = 0; ks < 24; ++ks) {
        const int k8 = ks * 32 + hi * 8;
        frag8 b0 = *(const frag8*)&Xs[lo * XSTR + k8];
        frag8 b1 = *(const frag8*)&Xs[(16 + lo) * XSTR + k8];
        #pragma unroll
        for (int ot = 0; ot < 4; ++ot) {
            frag8 a = *(const frag8*)&Wp[(size_t)(ot * 16) * KTOT + k8];
            acc[ot][0] = __builtin_amdgcn_mfma_f32_16x16x32_bf16(a, b0, acc[ot][0], 0, 0, 0);
            acc[ot][1] = __builtin_amdgcn_mfma_f32_16x16x32_bf16(a, b1, acc[ot][1], 0, 0, 0);
        }
    }

    // ---- store: D col = lane&15 (w), row = hi*4 + r (o within 16-tile) ----
    const int wb = wh * 32;
    #pragma unroll
    for (int ot = 0; ot < 4; ++ot) {
        #pragma unroll
        for (int nt = 0; nt < 2; ++nt) {
            int wcol = wb + nt * 16 + lo;
            if (wcol < WOUT) {
                #pragma unroll
                for (int r = 0; r < 4; ++r) {
                    int o = obase + ot * 16 + hi * 4 + r;
                    out[((size_t)(b * 256 + o) * HOUT + h) * WOUT + wcol] = acc[ot][nt][r];
                }
            }
        }
    }
}

extern "C" void kernel_launch(void* const* d_in, const int* in_sizes, int n_in,
                              void* d_out, int out_size, void* d_ws, size_t ws_size,
                              hipStream_t stream) {
    const float* x     = (const float*)d_in[0];   // (32,256,56,56)
    const float* lego  = (const float*)d_in[1];   // (64,64,3,1)
    const float* coefs = (const float*)d_in[2];   // (4,256,64,1,1)
    const float* comb  = (const float*)d_in[3];   // (4,256,64,1,1)
    float* out = (float*)d_out;                   // (32,256,19,58)

    unsigned short* Weff = (unsigned short*)d_ws; // 196,608 bf16 = 384 KB

    prep_weff<<<dim3(3, 256), 256, 0, stream>>>(lego, coefs, comb, Weff);
    conv_mfma<<<dim3(2, HOUT, 32), 256, 0, stream>>>(x, Weff, out);
}

// Round 4
// 209.047 us; speedup vs baseline: 1.4666x; 1.4666x over previous
//
#include <hip/hip_runtime.h>

// Problem constants
#define INC    256
#define HIN    56
#define WIN    56
#define HOUT   19
#define WOUT   58
#define KTOT   768          // K = kh*256 + c  (3 * 256); ks = k>>5 in [0,24)

typedef short frag8 __attribute__((ext_vector_type(8)));   // 8 bf16 bits (4 VGPRs)
typedef float f32x4 __attribute__((ext_vector_type(4)));   // MFMA accumulator

static __device__ __forceinline__ unsigned short f2bf(float f) {
    unsigned u = __float_as_uint(f);
    u += 0x7fffu + ((u >> 16) & 1u);      // round-to-nearest-even
    return (unsigned short)(u >> 16);
}

// ---------------------------------------------------------------------------
// prep_weff: fold sparse einsum into dense conv weights, emitted directly in
// MFMA A-fragment-linear order:
//   element (o, k):  o_tile=o>>4, m=o&15, ks=k>>5, kc=(k>>3)&3, j=k&7
//   Asw[(((o_tile*24 + ks)*64) + kc*16 + m)*8 + j] = coeff[i(c),o]*lego[idx][c&63][kh]
// so a wave's A-frag load (lane l = kc*16+m, 8 consecutive j) is one fully
// coalesced 1 KB global_load_dwordx4.
// Block (kx, o): 4 waves do the 64-lane argmax per split (first-max tie-break
// = jnp.argmax), then 256 threads emit one element each.
// ---------------------------------------------------------------------------
__global__ __launch_bounds__(256) void prep_weff(
    const float* __restrict__ lego,    // [64][64][3]
    const float* __restrict__ coefs,   // [4][256][64]
    const float* __restrict__ comb,    // [4][256][64]
    unsigned short* __restrict__ Asw)  // [16][24][64][8] bf16 bits
{
    __shared__ int   idxS[4];
    __shared__ float cofS[4];
    const int t  = threadIdx.x;
    const int kx = blockIdx.x;         // 0..2
    const int o  = blockIdx.y;         // 0..255
    const int wv = t >> 6, l = t & 63;

    float v  = comb[(wv * 256 + o) * 64 + l];
    int   bi = l;
    #pragma unroll
    for (int off = 32; off >= 1; off >>= 1) {
        float ov = __shfl_xor(v, off, 64);
        int   oi = __shfl_xor(bi, off, 64);
        if (ov > v || (ov == v && oi < bi)) { v = ov; bi = oi; }
    }
    if (l == 0) {
        idxS[wv] = bi;
        cofS[wv] = coefs[(wv * 256 + o) * 64 + bi];
    }
    __syncthreads();

    const int k  = kx * 256 + t;       // 0..767
    const int kh = k >> 8, c = k & 255;
    const int i  = c >> 6, cl = c & 63;
    float w = cofS[i] * lego[idxS[i] * 192 + cl * 3 + kh];

    const int o_tile = o >> 4, m = o & 15;
    const int ks = k >> 5, kc = (k >> 3) & 3, j = k & 7;
    Asw[((((size_t)o_tile * 24 + ks) * 64) + kc * 16 + m) * 8 + j] = f2bf(w);
}

// ---------------------------------------------------------------------------
// conv_mfma: dense 256x768 conv-GEMM per (w-half, h, b) block; 1216 blocks,
// 256 threads (4 waves). Out tile 256 o x 32 w, K = 768 (24 MFMA K-steps).
//
// Xs staged in B-fragment-linear order [ks][wtile][lane][8]:
//   B element (n=w, k): lane = ((k>>3)&3)*16 + (n&15), j = k&7
// -> every main-loop ds_read_b128 is lane-contiguous (conflict-free), every
// A load is a coalesced 1 KB dwordx4 from L2-hot Asw. One barrier per block.
// LDS 48 KB -> 3 blocks/CU.
// ---------------------------------------------------------------------------
__global__ __launch_bounds__(256) void conv_mfma(
    const float* __restrict__ x,             // [32][256][56][56]
    const unsigned short* __restrict__ Asw,  // [16][24][64][8]
    float* __restrict__ out)                 // [32][256][19][58]
{
    __shared__ unsigned short Xs[24 * 2 * 64 * 8];   // 48 KB, frag-linear

    const int t  = threadIdx.x;
    const int wh = blockIdx.x;               // 0/1 w-half
    const int h  = blockIdx.y;               // 0..18
    const int b  = blockIdx.z;               // 0..31

    // ---- stage X in B-frag order ----
    // thread (w = t&31, kg = t>>5): handles ks = kg*3 + s, s in 0..2.
    // Per (s,kc): 8 coalesced global loads (lanes 0..31 = consecutive w),
    // pack to one frag8, single ds_write_b128.
    {
        const float* xb = x + (size_t)b * (INC * HIN * WIN);
        const int w   = t & 31;
        const int kg  = t >> 5;
        const int col = wh * 32 - 1 + w;
        const bool colok = (unsigned)col < (unsigned)WIN;
        const int wtile = w >> 4;
        const int lbase = (w & 15);          // + kc*16
        const int rowbase = 3 * h - 1;

        for (int s = 0; s < 3; ++s) {
            const int ks  = kg * 3 + s;
            const int kh  = ks >> 3;               // ks*32 within one kh band
            const int row = rowbase + kh;
            const bool rowok = (unsigned)row < (unsigned)HIN;
            const float* xrow = xb + (size_t)row * WIN + col;
            const int cbase = (ks & 7) * 32;
            #pragma unroll
            for (int kc = 0; kc < 4; ++kc) {
                union { frag8 f; unsigned short u[8]; } pk;
                #pragma unroll
                for (int j = 0; j < 8; ++j) {
                    int c = cbase + kc * 8 + j;
                    float v = 0.f;
                    if (colok && rowok) v = xrow[(size_t)c * (HIN * WIN)];
                    pk.u[j] = f2bf(v);
                }
                *(frag8*)&Xs[(((ks * 2 + wtile) * 64) + kc * 16 + lbase) * 8] = pk.f;
            }
        }
    }
    __syncthreads();

    // ---- MFMA main loop ----
    const int l  = t & 63;
    const int lo = l & 15;                   // D: w col;  A row m / B col n
    const int hi = l >> 4;                   // D: o quad
    const int wv = t >> 6;                   // wave -> o range [wv*64, +64)

    f32x4 acc[4][2];
    #pragma unroll
    for (int ot = 0; ot < 4; ++ot)
        #pragma unroll
        for (int nt = 0; nt < 2; ++nt)
            acc[ot][nt] = (f32x4){0.f, 0.f, 0.f, 0.f};

    const frag8* Af = (const frag8*)Asw + ((size_t)(wv * 4) * 24) * 64 + l;
    const frag8* Xf = (const frag8*)Xs + l;

    #pragma unroll 8
    for (int ks = 0; ks < 24; ++ks) {
        frag8 b0 = Xf[(ks * 2) * 64];
        frag8 b1 = Xf[(ks * 2 + 1) * 64];
        #pragma unroll
        for (int ot = 0; ot < 4; ++ot) {
            frag8 a = Af[(ot * 24 + ks) * 64];
            acc[ot][0] = __builtin_amdgcn_mfma_f32_16x16x32_bf16(a, b0, acc[ot][0], 0, 0, 0);
            acc[ot][1] = __builtin_amdgcn_mfma_f32_16x16x32_bf16(a, b1, acc[ot][1], 0, 0, 0);
        }
    }

    // ---- store: D col = lo (w), row = hi*4 + r (o within 16-tile) ----
    const int wb = wh * 32;
    const int obase = wv * 64;
    #pragma unroll
    for (int ot = 0; ot < 4; ++ot) {
        #pragma unroll
        for (int nt = 0; nt < 2; ++nt) {
            int wcol = wb + nt * 16 + lo;
            if (wcol < WOUT) {
                #pragma unroll
                for (int r = 0; r < 4; ++r) {
                    int o = obase + ot * 16 + hi * 4 + r;
                    out[((size_t)(b * 256 + o) * HOUT + h) * WOUT + wcol] = acc[ot][nt][r];
                }
            }
        }
    }
}

extern "C" void kernel_launch(void* const* d_in, const int* in_sizes, int n_in,
                              void* d_out, int out_size, void* d_ws, size_t ws_size,
                              hipStream_t stream) {
    const float* x     = (const float*)d_in[0];   // (32,256,56,56)
    const float* lego  = (const float*)d_in[1];   // (64,64,3,1)
    const float* coefs = (const float*)d_in[2];   // (4,256,64,1,1)
    const float* comb  = (const float*)d_in[3];   // (4,256,64,1,1)
    float* out = (float*)d_out;                   // (32,256,19,58)

    unsigned short* Asw = (unsigned short*)d_ws;  // 196,608 bf16 = 384 KB

    prep_weff<<<dim3(3, 256), 256, 0, stream>>>(lego, coefs, comb, Asw);
    conv_mfma<<<dim3(2, HOUT, 32), 256, 0, stream>>>(x, Asw, out);
}

// Round 5
// 194.187 us; speedup vs baseline: 1.5789x; 1.0765x over previous
//
#include <hip/hip_runtime.h>

// Problem constants
#define INC    256
#define HIN    56
#define WIN    56
#define HOUT   19
#define WOUT   58
#define KTOT   768          // K = kh*256 + c; 24 MFMA K-steps (ks), 2 chunks x 12

typedef short frag8 __attribute__((ext_vector_type(8)));   // 8 bf16 bits (4 VGPRs)
typedef float f32x4 __attribute__((ext_vector_type(4)));   // MFMA accumulator

static __device__ __forceinline__ unsigned short f2bf(float f) {
    unsigned u = __float_as_uint(f);
    u += 0x7fffu + ((u >> 16) & 1u);      // round-to-nearest-even
    return (unsigned short)(u >> 16);
}

// ---------------------------------------------------------------------------
// prep_weff: fold sparse einsum into dense conv weights, emitted in MFMA
// A-fragment-linear order:
//   element (o, k):  o_tile=o>>4, m=o&15, ks=k>>5, kc=(k>>3)&3, j=k&7
//   Asw[(((o_tile*24 + ks)*64) + kc*16 + m)*8 + j]
//     = coeff[i(c),o] * lego[idx[i(c),o]][c&63][kh]           (bf16)
// ---------------------------------------------------------------------------
__global__ __launch_bounds__(256) void prep_weff(
    const float* __restrict__ lego,    // [64][64][3]
    const float* __restrict__ coefs,   // [4][256][64]
    const float* __restrict__ comb,    // [4][256][64]
    unsigned short* __restrict__ Asw)  // [16][24][64][8] bf16 bits
{
    __shared__ int   idxS[4];
    __shared__ float cofS[4];
    const int t  = threadIdx.x;
    const int kx = blockIdx.x;         // 0..2
    const int o  = blockIdx.y;         // 0..255
    const int wv = t >> 6, l = t & 63;

    float v  = comb[(wv * 256 + o) * 64 + l];
    int   bi = l;
    #pragma unroll
    for (int off = 32; off >= 1; off >>= 1) {
        float ov = __shfl_xor(v, off, 64);
        int   oi = __shfl_xor(bi, off, 64);
        if (ov > v || (ov == v && oi < bi)) { v = ov; bi = oi; }
    }
    if (l == 0) {
        idxS[wv] = bi;
        cofS[wv] = coefs[(wv * 256 + o) * 64 + bi];
    }
    __syncthreads();

    const int k  = kx * 256 + t;       // 0..767
    const int kh = k >> 8, c = k & 255;
    const int i  = c >> 6, cl = c & 63;
    float w = cofS[i] * lego[idxS[i] * 192 + cl * 3 + kh];

    const int o_tile = o >> 4, m = o & 15;
    const int ks = k >> 5, kc = (k >> 3) & 3, j = k & 7;
    Asw[((((size_t)o_tile * 24 + ks) * 64) + kc * 16 + m) * 8 + j] = f2bf(w);
}

// ---------------------------------------------------------------------------
// conv_mfma: dense 256x768 conv-GEMM per (w-half, h, b) block; 1216 blocks,
// 256 threads (4 waves). Out tile 256 o x 32 w. K processed in 2 chunks of
// 384 (12 MFMA K-steps each) so Xs = 24 KB ->
//   blocks/CU = min(LDS 160/24=6, VGPR 512/102=5 waves/SIMD) = 5
//   -> 1280 slots >= 1216 blocks: ENTIRE GRID CO-RESIDENT, 20 waves/CU.
// __launch_bounds__(256,5): VGPR cap 102 — enough for acc(32) + depth-1
// A/B prefetch (24) + addressing; was 68 with no slack (the R4 latency wall).
// All main-loop A loads: coalesced 1 KB dwordx4 from L2-hot Asw; all B reads:
// lane-contiguous ds_read_b128 (0 conflicts, measured R4).
// ---------------------------------------------------------------------------
__global__ __launch_bounds__(256, 5) void conv_mfma(
    const float* __restrict__ x,             // [32][256][56][56]
    const unsigned short* __restrict__ Asw,  // [16][24][64][8]
    float* __restrict__ out)                 // [32][256][19][58]
{
    __shared__ unsigned short Xs[12 * 2 * 64 * 8];   // 24 KB, B-frag-linear

    const int t  = threadIdx.x;
    const int wh = blockIdx.x;               // 0/1 w-half
    const int h  = blockIdx.y;               // 0..18
    const int b  = blockIdx.z;               // 0..31

    const int l  = t & 63;
    const int lo = l & 15;
    const int hi = l >> 4;
    const int wv = t >> 6;

    f32x4 acc[4][2];
    #pragma unroll
    for (int ot = 0; ot < 4; ++ot)
        #pragma unroll
        for (int nt = 0; nt < 2; ++nt)
            acc[ot][nt] = (f32x4){0.f, 0.f, 0.f, 0.f};

    // staging mapping
    const float* xb = x + (size_t)b * (INC * HIN * WIN);
    const int w     = t & 31;
    const int kg    = t >> 5;                // 0..7
    const int col   = wh * 32 - 1 + w;
    const bool colok = (unsigned)col < (unsigned)WIN;
    const int wtile = w >> 4;
    const int lbase = w & 15;
    const int rowbase = 3 * h - 1;

    const frag8* Af = (const frag8*)Asw + ((size_t)(wv * 4) * 24) * 64 + l;
    const frag8* Xf = (const frag8*)Xs + l;

    for (int c2 = 0; c2 < 2; ++c2) {
        // ---- stage chunk c2: thread packs 6 frag8s (48 coalesced loads) ----
        #pragma unroll
        for (int q = 0; q < 6; ++q) {
            int p   = kg * 6 + q;            // 0..47
            int ksl = p >> 2, kc = p & 3;    // ksl 0..11
            int kgl = c2 * 384 + ksl * 32 + kc * 8;
            int kh  = kgl >> 8, c0 = kgl & 255;
            int row = rowbase + kh;
            bool ok = colok && ((unsigned)row < (unsigned)HIN);
            const float* xp = xb + (size_t)c0 * (HIN * WIN) + row * WIN + col;
            union { frag8 f; unsigned short u[8]; } pk;
            #pragma unroll
            for (int j = 0; j < 8; ++j) {
                float v = ok ? xp[(size_t)j * (HIN * WIN)] : 0.f;
                pk.u[j] = f2bf(v);
            }
            *(frag8*)&Xs[(((ksl * 2 + wtile) * 64) + kc * 16 + lbase) * 8] = pk.f;
        }
        __syncthreads();

        // ---- MFMA over this chunk, depth-1 software pipeline ----
        const int ksb = c2 * 12;             // global ks base
        frag8 a[4], an[4], b0, b1, b0n, b1n;
        #pragma unroll
        for (int ot = 0; ot < 4; ++ot) a[ot] = Af[(ot * 24 + ksb) * 64];
        b0 = Xf[0];
        b1 = Xf[64];

        #pragma unroll
        for (int ks = 0; ks < 11; ++ks) {
            // issue next-step loads first (in flight during MFMAs)
            #pragma unroll
            for (int ot = 0; ot < 4; ++ot) an[ot] = Af[(ot * 24 + ksb + ks + 1) * 64];
            b0n = Xf[((ks + 1) * 2) * 64];
            b1n = Xf[((ks + 1) * 2 + 1) * 64];

            #pragma unroll
            for (int ot = 0; ot < 4; ++ot) {
                acc[ot][0] = __builtin_amdgcn_mfma_f32_16x16x32_bf16(a[ot], b0, acc[ot][0], 0, 0, 0);
                acc[ot][1] = __builtin_amdgcn_mfma_f32_16x16x32_bf16(a[ot], b1, acc[ot][1], 0, 0, 0);
            }
            #pragma unroll
            for (int ot = 0; ot < 4; ++ot) a[ot] = an[ot];
            b0 = b0n; b1 = b1n;
        }
        #pragma unroll
        for (int ot = 0; ot < 4; ++ot) {
            acc[ot][0] = __builtin_amdgcn_mfma_f32_16x16x32_bf16(a[ot], b0, acc[ot][0], 0, 0, 0);
            acc[ot][1] = __builtin_amdgcn_mfma_f32_16x16x32_bf16(a[ot], b1, acc[ot][1], 0, 0, 0);
        }
        __syncthreads();                     // LDS reads done before restage
    }

    // ---- store: D col = lo (w), row = hi*4 + r (o within 16-tile) ----
    const int wb = wh * 32;
    const int obase = wv * 64;
    #pragma unroll
    for (int ot = 0; ot < 4; ++ot) {
        #pragma unroll
        for (int nt = 0; nt < 2; ++nt) {
            int wcol = wb + nt * 16 + lo;
            if (wcol < WOUT) {
                #pragma unroll
                for (int r = 0; r < 4; ++r) {
                    int o = obase + ot * 16 + hi * 4 + r;
                    out[((size_t)(b * 256 + o) * HOUT + h) * WOUT + wcol] = acc[ot][nt][r];
                }
            }
        }
    }
}

extern "C" void kernel_launch(void* const* d_in, const int* in_sizes, int n_in,
                              void* d_out, int out_size, void* d_ws, size_t ws_size,
                              hipStream_t stream) {
    const float* x     = (const float*)d_in[0];   // (32,256,56,56)
    const float* lego  = (const float*)d_in[1];   // (64,64,3,1)
    const float* coefs = (const float*)d_in[2];   // (4,256,64,1,1)
    const float* comb  = (const float*)d_in[3];   // (4,256,64,1,1)
    float* out = (float*)d_out;                   // (32,256,19,58)

    unsigned short* Asw = (unsigned short*)d_ws;  // 196,608 bf16 = 384 KB

    prep_weff<<<dim3(3, 256), 256, 0, stream>>>(lego, coefs, comb, Asw);
    conv_mfma<<<dim3(2, HOUT, 32), 256, 0, stream>>>(x, Asw, out);
}